// Round 20
// baseline (47.212 us; speedup 1.0000x reference)
//
#include <hip/hip_runtime.h>

#define LRELU(v) ((v) >= 0.f ? (v) : 0.2f*(v))

// ---- conv1: named-register row access ------------------------------------
#define ROROW(P, RB) \
    const float P##0=ro[(RB)+0], P##1=ro[(RB)+1], P##2=ro[(RB)+2], \
        P##3=ro[(RB)+3], P##4=ro[(RB)+4], P##5=ro[(RB)+5], \
        P##6=ro[(RB)+6], P##7=ro[(RB)+7], P##8=ro[(RB)+8];

#define C1X(X0,X1,X2,X3) \
    (wa.x*A##X0 + wa.y*A##X1 + wa.z*A##X2 + wa.w*A##X3 \
   + wb.x*B##X0 + wb.y*B##X1 + wb.z*B##X2 + wb.w*B##X3 \
   + wc.x*C##X0 + wc.y*C##X1 + wc.z*C##X2 + wc.w*C##X3 \
   + wd.x*D##X0 + wd.y*D##X1 + wd.z*D##X2 + wd.w*D##X3)

// ---- conv2: named-register h-row access: E<i> = element i of 36-float row -
#define E0 q0.x
#define E1 q0.y
#define E2 q0.z
#define E3 q0.w
#define E4 q1.x
#define E5 q1.y
#define E6 q1.z
#define E7 q1.w
#define E8 q2.x
#define E9 q2.y
#define E10 q2.z
#define E11 q2.w
#define E12 q3.x
#define E13 q3.y
#define E14 q3.z
#define E15 q3.w
#define E16 q4.x
#define E17 q4.y
#define E18 q4.z
#define E19 q4.w
#define E20 q5.x
#define E21 q5.y
#define E22 q5.z
#define E23 q5.w
#define E24 q6.x
#define E25 q6.y
#define E26 q6.z
#define E27 q6.w
#define E28 q7.x
#define E29 q7.y
#define E30 q7.z
#define E31 q7.w
#define E32 q8.x
#define E33 q8.y
#define E34 q8.z
#define E35 q8.w

#define AT(P, A, B, C, D) a##P += w.x*E##A + w.y*E##B + w.z*E##C + w.w*E##D;

#define RED9A(M) \
    a0+=__shfl_xor(a0,M); a1+=__shfl_xor(a1,M); a2+=__shfl_xor(a2,M); \
    a3+=__shfl_xor(a3,M); a4+=__shfl_xor(a4,M); a5+=__shfl_xor(a5,M); \
    a6+=__shfl_xor(a6,M); a7+=__shfl_xor(a7,M); a8+=__shfl_xor(a8,M);

// w2 chunk staging (32-oc slice), fully named regs
#define LD1(RK, K, BASE) { const int fidx_ = t + (K)*256; \
    const int woc_ = fidx_ >> 5, q4_ = fidx_ & 31; \
    RK = ((const float4*)w2)[(oc0 + woc_)*128 + (BASE) + q4_]; }
#define LDALL(BASE) LD1(r0,0,BASE) LD1(r1,1,BASE) LD1(r2,2,BASE) LD1(r3,3,BASE)
#define ST1(RK, K) { const int fidx_ = t + (K)*256; \
    const int woc_ = fidx_ >> 5, q4_ = fidx_ & 31; \
    *((float4*)&w2s[woc_*128 + ((q4_*4) ^ ((woc_ & 7) << 2))]) = RK; }
#define STALL ST1(r0,0) ST1(r1,1) ST1(r2,2) ST1(r3,3)

// ---------------- Kernel A: conv stack v6 ----------------------------------
// Single change vs round-19: thread = (ocl = t>>3, ich = t&7) puts the 8-way
// ic split in LANE bits 0-2 -> shfl_xor reduction replaces the red[] LDS
// round-trip (-9 LDS ops/thread, -2 barriers, -9.2KB LDS).
__global__ __launch_bounds__(256) void convf_kernel(
    const float* __restrict__ readout, const float* __restrict__ energy,
    const float* __restrict__ w1, const float* __restrict__ w2,
    const float* __restrict__ W1, float* __restrict__ f_ws,
    float* __restrict__ W1T)
{
    const int bid = blockIdx.x;
    const int n   = bid >> 1;
    const int och = bid & 1;
    const int oc0 = och << 5;
    const int t = threadIdx.x;
    __shared__ float ro[81];
    __shared__ float h1[1152];
    __shared__ float w2s[4096];

    if (t < 81) ro[t] = readout[n*81 + t];
    __syncthreads();

    if (och == 0 && t < 64) {
        float v = ro[t];
        if (t < 17) v += ro[t + 64];
        #pragma unroll
        for (int m = 32; m; m >>= 1) v += __shfl_down(v, m);
        if (t == 0) f_ws[n*577 + 576] = fabsf(v - energy[n]);
    }

    if (t < 192) {
        const int oc1 = t & 31, y = t >> 5;
        const float4* wp4 = (const float4*)&w1[oc1*16];
        const float4 wa = wp4[0], wb = wp4[1], wc = wp4[2], wd = wp4[3];
        const int rb0 = y*9;
        ROROW(A, rb0)
        ROROW(B, rb0+9)
        ROROW(C, rb0+18)
        ROROW(D, rb0+27)
        float* hp = &h1[oc1*36 + y*6];
        float v;
        v = C1X(0,1,2,3); hp[0] = LRELU(v);
        v = C1X(1,2,3,4); hp[1] = LRELU(v);
        v = C1X(2,3,4,5); hp[2] = LRELU(v);
        v = C1X(3,4,5,6); hp[3] = LRELU(v);
        v = C1X(4,5,6,7); hp[4] = LRELU(v);
        v = C1X(5,6,7,8); hp[5] = LRELU(v);
    }

    float4 r0, r1, r2, r3;
    LDALL(0)
    __syncthreads();

    // v6 mapping: ocl in t-bits 3-7, ich in lane bits 0-2
    const int ocl = t >> 3, ich = t & 7;
    float a0=0.f,a1=0.f,a2=0.f,a3=0.f,a4=0.f,a5=0.f,a6=0.f,a7=0.f,a8=0.f;
    const int wbase = ocl*128;
    const int wswz  = (ocl & 7) << 2;

    for (int chunk = 0; chunk < 4; chunk++) {
        STALL
        __syncthreads();
        if (chunk < 3) { LDALL((chunk+1)*32) }
        {
            const int icw = ich;
            const int ic  = chunk*8 + ich;
            const float4* hp = (const float4*)&h1[ic*36];
            float4 q0=hp[0], q1=hp[1], q2=hp[2], q3=hp[3], q4=hp[4],
                   q5=hp[5], q6=hp[6], q7=hp[7], q8=hp[8];
            { float4 w = *((const float4*)&w2s[wbase + ((icw*16 + 0) ^ wswz)]);
              AT(0, 0,1,2,3)    AT(1, 1,2,3,4)    AT(2, 2,3,4,5)
              AT(3, 6,7,8,9)    AT(4, 7,8,9,10)   AT(5, 8,9,10,11)
              AT(6, 12,13,14,15) AT(7, 13,14,15,16) AT(8, 14,15,16,17) }
            { float4 w = *((const float4*)&w2s[wbase + ((icw*16 + 4) ^ wswz)]);
              AT(0, 6,7,8,9)    AT(1, 7,8,9,10)   AT(2, 8,9,10,11)
              AT(3, 12,13,14,15) AT(4, 13,14,15,16) AT(5, 14,15,16,17)
              AT(6, 18,19,20,21) AT(7, 19,20,21,22) AT(8, 20,21,22,23) }
            { float4 w = *((const float4*)&w2s[wbase + ((icw*16 + 8) ^ wswz)]);
              AT(0, 12,13,14,15) AT(1, 13,14,15,16) AT(2, 14,15,16,17)
              AT(3, 18,19,20,21) AT(4, 19,20,21,22) AT(5, 20,21,22,23)
              AT(6, 24,25,26,27) AT(7, 25,26,27,28) AT(8, 26,27,28,29) }
            { float4 w = *((const float4*)&w2s[wbase + ((icw*16 + 12) ^ wswz)]);
              AT(0, 18,19,20,21) AT(1, 19,20,21,22) AT(2, 20,21,22,23)
              AT(3, 24,25,26,27) AT(4, 25,26,27,28) AT(5, 26,27,28,29)
              AT(6, 30,31,32,33) AT(7, 31,32,33,34) AT(8, 32,33,34,35) }
        }
        __syncthreads();
    }

    // in-register reduction over ich (lane bits 0-2)
    RED9A(1) RED9A(2) RED9A(4)

    if (ich == 0) {
        float* fo = &f_ws[n*577 + (oc0 + ocl)*9];
        float v;
        v=a0; fo[0]=LRELU(v); v=a1; fo[1]=LRELU(v); v=a2; fo[2]=LRELU(v);
        v=a3; fo[3]=LRELU(v); v=a4; fo[4]=LRELU(v); v=a5; fo[5]=LRELU(v);
        v=a6; fo[6]=LRELU(v); v=a7; fo[7]=LRELU(v); v=a8; fo[8]=LRELU(v);
    }

    if (bid < 8) {
        for (int idx = t; idx < 2436; idx += 256) {
            const int g = bid*2436 + idx;
            const int u = g & 31, a = g >> 5;
            W1T[g] = W1[u*609 + a];
        }
    }
}

// ---------------- Kernel B: M = F @ T, v3 (round-17, unchanged) ------------
__global__ __launch_bounds__(1024) void mgemm_kernel(
    const float* __restrict__ F, const float* __restrict__ T,
    float* __restrict__ M)
{
    const int t = threadIdx.x;
    const int rb = blockIdx.x >> 2;          // 64 row tiles of 8
    const int cb = blockIdx.x & 3;           // 4 col tiles of 128
    const int ws = __builtin_amdgcn_readfirstlane(t >> 6);  // wave 0..15
    const int lane = t & 63;
    const int c0 = cb*128 + lane*2;
    const int k0 = ws*36;
    const int k1 = (ws == 15) ? 577 : (k0 + 36);
    const int r0 = rb*8;
    __shared__ float red[8*1032];

    const float* fbase = F + r0*577;
    float x0=0.f,y0=0.f, x1=0.f,y1=0.f, x2=0.f,y2=0.f, x3=0.f,y3=0.f,
          x4=0.f,y4=0.f, x5=0.f,y5=0.f, x6=0.f,y6=0.f, x7=0.f,y7=0.f;
    #pragma unroll 4
    for (int k = k0; k < k1; ++k) {
        const float2 tv = *(const float2*)&T[k*512 + c0];
        const float* fr = fbase + k;
        const float f0v = fr[0],    f1v = fr[577],  f2v = fr[1154], f3v = fr[1731];
        const float f4v = fr[2308], f5v = fr[2885], f6v = fr[3462], f7v = fr[4039];
        x0 += f0v*tv.x; y0 += f0v*tv.y;
        x1 += f1v*tv.x; y1 += f1v*tv.y;
        x2 += f2v*tv.x; y2 += f2v*tv.y;
        x3 += f3v*tv.x; y3 += f3v*tv.y;
        x4 += f4v*tv.x; y4 += f4v*tv.y;
        x5 += f5v*tv.x; y5 += f5v*tv.y;
        x6 += f6v*tv.x; y6 += f6v*tv.y;
        x7 += f7v*tv.x; y7 += f7v*tv.y;
    }

    const int cl2 = lane*2;
    if (ws < 8) {
        float* rp = &red[ws*1032];
        *(float2*)&rp[0*128 + cl2] = make_float2(x0, y0);
        *(float2*)&rp[1*128 + cl2] = make_float2(x1, y1);
        *(float2*)&rp[2*128 + cl2] = make_float2(x2, y2);
        *(float2*)&rp[3*128 + cl2] = make_float2(x3, y3);
        *(float2*)&rp[4*128 + cl2] = make_float2(x4, y4);
        *(float2*)&rp[5*128 + cl2] = make_float2(x5, y5);
        *(float2*)&rp[6*128 + cl2] = make_float2(x6, y6);
        *(float2*)&rp[7*128 + cl2] = make_float2(x7, y7);
    }
    __syncthreads();
    if (ws >= 8) {
        float* rp = &red[(ws-8)*1032];
        float2 v;
        v = *(float2*)&rp[0*128 + cl2]; v.x += x0; v.y += y0; *(float2*)&rp[0*128 + cl2] = v;
        v = *(float2*)&rp[1*128 + cl2]; v.x += x1; v.y += y1; *(float2*)&rp[1*128 + cl2] = v;
        v = *(float2*)&rp[2*128 + cl2]; v.x += x2; v.y += y2; *(float2*)&rp[2*128 + cl2] = v;
        v = *(float2*)&rp[3*128 + cl2]; v.x += x3; v.y += y3; *(float2*)&rp[3*128 + cl2] = v;
        v = *(float2*)&rp[4*128 + cl2]; v.x += x4; v.y += y4; *(float2*)&rp[4*128 + cl2] = v;
        v = *(float2*)&rp[5*128 + cl2]; v.x += x5; v.y += y5; *(float2*)&rp[5*128 + cl2] = v;
        v = *(float2*)&rp[6*128 + cl2]; v.x += x6; v.y += y6; *(float2*)&rp[6*128 + cl2] = v;
        v = *(float2*)&rp[7*128 + cl2]; v.x += x7; v.y += y7; *(float2*)&rp[7*128 + cl2] = v;
    }
    __syncthreads();
    {
        const int row = t >> 7, col = t & 127;
        const int o = row*128 + col;
        float v = 0.f;
        #pragma unroll
        for (int p = 0; p < 8; p++) v += red[p*1032 + o];
        M[(r0 + row)*512 + cb*128 + col] = v;
    }
}

// ---------------- Kernel C: pairwise (round-14 body, grid 512) -------------
#define LDM(R0, R1, R2, R3, JOFF) { \
    const float4* p_ = (const float4*)&M[(j0+jl+(JOFF))*512 + b*16]; \
    R0 = p_[0]; R1 = p_[1]; R2 = p_[2]; R3 = p_[3]; }

#define S16(P0, P1, P2, P3) \
  (fabsf(v0.x-P0.x)+fabsf(v0.y-P0.y)+fabsf(v0.z-P0.z)+fabsf(v0.w-P0.w) \
  +fabsf(v1.x-P1.x)+fabsf(v1.y-P1.y)+fabsf(v1.z-P1.z)+fabsf(v1.w-P1.w) \
  +fabsf(v2.x-P2.x)+fabsf(v2.y-P2.y)+fabsf(v2.z-P2.z)+fabsf(v2.w-P2.w) \
  +fabsf(v3.x-P3.x)+fabsf(v3.y-P3.y)+fabsf(v3.z-P3.z)+fabsf(v3.w-P3.w))

__global__ __launch_bounds__(256) void pairwise_kernel(
    const float* __restrict__ M, float* __restrict__ o_part) // (32,512,32)
{
    const int jt  = blockIdx.x >> 5;
    const int isp = blockIdx.x & 31;
    const int t = threadIdx.x;
    const int b = t & 31, jl = t >> 5;
    const int j0 = jt * 32;
    __shared__ float mi[16*572];

    float4 mA0,mA1,mA2,mA3, mB0,mB1,mB2,mB3, mC0,mC1,mC2,mC3, mD0,mD1,mD2,mD3;
    LDM(mA0,mA1,mA2,mA3, 0)
    LDM(mB0,mB1,mB2,mB3, 8)
    LDM(mC0,mC1,mC2,mC3, 16)
    LDM(mD0,mD1,mD2,mD3, 24)

    const int i0 = isp * 16;
    #pragma unroll
    for (int k = 0; k < 8; k++) {
        const int q = k*256 + t;
        const int r = q >> 7;
        const int x = (q & 127) * 4;
        float4 v = *(const float4*)&M[(i0+r)*512 + x];
        *(float4*)&mi[r*572 + x + ((x>>5)<<2)] = v;
    }
    __syncthreads();

    float acc0 = 0.f, acc1 = 0.f, acc2 = 0.f, acc3 = 0.f;
    const int lbase = b*16 + ((b>>1)<<2);

    #pragma unroll 4
    for (int r = 0; r < 16; r++) {
        const float4* q_ = (const float4*)&mi[r*572 + lbase];
        const float4 v0 = q_[0], v1 = q_[1], v2 = q_[2], v3 = q_[3];
        acc0 += __expf(-(S16(mA0,mA1,mA2,mA3)));
        acc1 += __expf(-(S16(mB0,mB1,mB2,mB3)));
        acc2 += __expf(-(S16(mC0,mC1,mC2,mC3)));
        acc3 += __expf(-(S16(mD0,mD1,mD2,mD3)));
    }
    const int ob = isp*16384 + b;
    o_part[ob + (j0+jl   )*32] = acc0;
    o_part[ob + (j0+jl+8 )*32] = acc1;
    o_part[ob + (j0+jl+16)*32] = acc2;
    o_part[ob + (j0+jl+24)*32] = acc3;
}

// ---------------- Kernel D: MLP head (round-14 body) -----------------------
__global__ __launch_bounds__(256) void mlp_kernel(
    const float* __restrict__ f, const float* __restrict__ o_part,
    const float* __restrict__ W1T, const float* __restrict__ b1v,
    const float* __restrict__ W2, const float* __restrict__ b2v,
    float* __restrict__ out)
{
    const int j = blockIdx.x;
    const int t = threadIdx.x;
    __shared__ float xs[609];
    __shared__ float red[256];

    for (int a = t; a < 577; a += 256) xs[a] = f[j*577 + a];
    {
        const int bb = t & 31, g = t >> 5;
        float ov = 0.f;
        #pragma unroll
        for (int k = 0; k < 4; k++)
            ov += o_part[(g + 8*k)*16384 + j*32 + bb];
        red[t] = ov;
    }
    __syncthreads();
    if (t < 32) {
        float ov = 0.f;
        #pragma unroll
        for (int g = 0; g < 8; g++) ov += red[t + g*32];
        xs[577 + t] = ov;
    }
    __syncthreads();

    const int u = t & 31, seg = t >> 5;
    float p = 0.f;
    #pragma unroll 4
    for (int a = seg; a < 609; a += 8)
        p += xs[a] * W1T[a*32 + u];
    red[t] = p;
    __syncthreads();

    if (t < 32) {
        float hid = red[t];
        #pragma unroll
        for (int s = 1; s < 8; s++) hid += red[t + s*32];
        hid += b1v[t];
        hid = LRELU(hid);
        float pr = hid * W2[t];
        #pragma unroll
        for (int mk = 16; mk; mk >>= 1) pr += __shfl_xor(pr, mk);
        if (t == 0) out[j] = 1.f / (1.f + __expf(-(pr + b2v[0])));
    }
}

extern "C" void kernel_launch(void* const* d_in, const int* in_sizes, int n_in,
                              void* d_out, int out_size, void* d_ws, size_t ws_size,
                              hipStream_t stream) {
    const float* readout = (const float*)d_in[0];
    const float* energy  = (const float*)d_in[1];
    const float* w1      = (const float*)d_in[2];
    const float* w2      = (const float*)d_in[3];
    const float* Tm      = (const float*)d_in[4];
    const float* W1      = (const float*)d_in[5];
    const float* b1v     = (const float*)d_in[6];
    const float* W2      = (const float*)d_in[7];
    const float* b2v     = (const float*)d_in[8];
    float* out = (float*)d_out;

    char* ws = (char*)d_ws;
    float* f_ws   = (float*)(ws);                                       // 512*577
    float* M_ws   = (float*)(ws + 512*577*4);                           // 512*512
    float* o_ws   = (float*)(ws + 512*577*4 + 512*512*4);               // 32*512*32
    float* W1T_ws = (float*)(ws + 512*577*4 + 512*512*4 + 32*512*32*4); // 609*32

    convf_kernel   <<<1024, 256, 0, stream>>>(readout, energy, w1, w2, W1, f_ws, W1T_ws);
    mgemm_kernel   <<<256, 1024, 0, stream>>>(f_ws, Tm, M_ws);
    pairwise_kernel<<<512, 256, 0, stream>>>(M_ws, o_ws);
    mlp_kernel     <<<512, 256, 0, stream>>>(f_ws, o_ws, W1T_ws, b1v, W2, b2v, out);
}

// Round 21
// 45.620 us; speedup vs baseline: 1.0349x; 1.0349x over previous
//
#include <hip/hip_runtime.h>

#define LRELU(v) ((v) >= 0.f ? (v) : 0.2f*(v))

// ---- conv1: named-register row access ------------------------------------
#define ROROW(P, RB) \
    const float P##0=ro[(RB)+0], P##1=ro[(RB)+1], P##2=ro[(RB)+2], \
        P##3=ro[(RB)+3], P##4=ro[(RB)+4], P##5=ro[(RB)+5], \
        P##6=ro[(RB)+6], P##7=ro[(RB)+7], P##8=ro[(RB)+8];

#define C1X(X0,X1,X2,X3) \
    (wa.x*A##X0 + wa.y*A##X1 + wa.z*A##X2 + wa.w*A##X3 \
   + wb.x*B##X0 + wb.y*B##X1 + wb.z*B##X2 + wb.w*B##X3 \
   + wc.x*C##X0 + wc.y*C##X1 + wc.z*C##X2 + wc.w*C##X3 \
   + wd.x*D##X0 + wd.y*D##X1 + wd.z*D##X2 + wd.w*D##X3)

// ---- conv2: named-register h-row access: E<i> = element i of 36-float row -
#define E0 q0.x
#define E1 q0.y
#define E2 q0.z
#define E3 q0.w
#define E4 q1.x
#define E5 q1.y
#define E6 q1.z
#define E7 q1.w
#define E8 q2.x
#define E9 q2.y
#define E10 q2.z
#define E11 q2.w
#define E12 q3.x
#define E13 q3.y
#define E14 q3.z
#define E15 q3.w
#define E16 q4.x
#define E17 q4.y
#define E18 q4.z
#define E19 q4.w
#define E20 q5.x
#define E21 q5.y
#define E22 q5.z
#define E23 q5.w
#define E24 q6.x
#define E25 q6.y
#define E26 q6.z
#define E27 q6.w
#define E28 q7.x
#define E29 q7.y
#define E30 q7.z
#define E31 q7.w
#define E32 q8.x
#define E33 q8.y
#define E34 q8.z
#define E35 q8.w

#define AT(P, A, B, C, D) a##P += w.x*E##A + w.y*E##B + w.z*E##C + w.w*E##D;

// w2 chunk staging (32-oc slice), fully named regs
#define LD1(RK, K, BASE) { const int fidx_ = t + (K)*256; \
    const int woc_ = fidx_ >> 5, q4_ = fidx_ & 31; \
    RK = ((const float4*)w2)[(oc0 + woc_)*128 + (BASE) + q4_]; }
#define LDALL(BASE) LD1(r0,0,BASE) LD1(r1,1,BASE) LD1(r2,2,BASE) LD1(r3,3,BASE)
#define ST1(RK, K) { const int fidx_ = t + (K)*256; \
    const int woc_ = fidx_ >> 5, q4_ = fidx_ & 31; \
    *((float4*)&w2s[woc_*128 + ((q4_*4) ^ ((woc_ & 7) << 2))]) = RK; }
#define STALL ST1(r0,0) ST1(r1,1) ST1(r2,2) ST1(r3,3)

// ---------------- Kernel A: conv stack (round-14 body) ---------------------
__global__ __launch_bounds__(256) void convf_kernel(
    const float* __restrict__ readout, const float* __restrict__ energy,
    const float* __restrict__ w1, const float* __restrict__ w2,
    const float* __restrict__ W1, float* __restrict__ f_ws,
    float* __restrict__ W1T)
{
    const int bid = blockIdx.x;
    const int n   = bid >> 1;
    const int och = bid & 1;
    const int oc0 = och << 5;
    const int t = threadIdx.x;
    __shared__ float ro[81];
    __shared__ float h1[1152];
    __shared__ float w2s[4096];
    __shared__ float red[2304];

    if (t < 81) ro[t] = readout[n*81 + t];
    __syncthreads();

    if (och == 0 && t < 64) {
        float v = ro[t];
        if (t < 17) v += ro[t + 64];
        #pragma unroll
        for (int m = 32; m; m >>= 1) v += __shfl_down(v, m);
        if (t == 0) f_ws[n*577 + 576] = fabsf(v - energy[n]);
    }

    if (t < 192) {
        const int oc1 = t & 31, y = t >> 5;
        const float4* wp4 = (const float4*)&w1[oc1*16];
        const float4 wa = wp4[0], wb = wp4[1], wc = wp4[2], wd = wp4[3];
        const int rb0 = y*9;
        ROROW(A, rb0)
        ROROW(B, rb0+9)
        ROROW(C, rb0+18)
        ROROW(D, rb0+27)
        float* hp = &h1[oc1*36 + y*6];
        float v;
        v = C1X(0,1,2,3); hp[0] = LRELU(v);
        v = C1X(1,2,3,4); hp[1] = LRELU(v);
        v = C1X(2,3,4,5); hp[2] = LRELU(v);
        v = C1X(3,4,5,6); hp[3] = LRELU(v);
        v = C1X(4,5,6,7); hp[4] = LRELU(v);
        v = C1X(5,6,7,8); hp[5] = LRELU(v);
    }

    float4 r0, r1, r2, r3;
    LDALL(0)
    __syncthreads();

    const int ich = t >> 5, ocl = t & 31;
    float a0=0.f,a1=0.f,a2=0.f,a3=0.f,a4=0.f,a5=0.f,a6=0.f,a7=0.f,a8=0.f;
    const int wbase = ocl*128;
    const int wswz  = (ocl & 7) << 2;

    for (int chunk = 0; chunk < 4; chunk++) {
        STALL
        __syncthreads();
        if (chunk < 3) { LDALL((chunk+1)*32) }
        {
            const int icw = ich;
            const int ic  = chunk*8 + ich;
            const float4* hp = (const float4*)&h1[ic*36];
            float4 q0=hp[0], q1=hp[1], q2=hp[2], q3=hp[3], q4=hp[4],
                   q5=hp[5], q6=hp[6], q7=hp[7], q8=hp[8];
            { float4 w = *((const float4*)&w2s[wbase + ((icw*16 + 0) ^ wswz)]);
              AT(0, 0,1,2,3)    AT(1, 1,2,3,4)    AT(2, 2,3,4,5)
              AT(3, 6,7,8,9)    AT(4, 7,8,9,10)   AT(5, 8,9,10,11)
              AT(6, 12,13,14,15) AT(7, 13,14,15,16) AT(8, 14,15,16,17) }
            { float4 w = *((const float4*)&w2s[wbase + ((icw*16 + 4) ^ wswz)]);
              AT(0, 6,7,8,9)    AT(1, 7,8,9,10)   AT(2, 8,9,10,11)
              AT(3, 12,13,14,15) AT(4, 13,14,15,16) AT(5, 14,15,16,17)
              AT(6, 18,19,20,21) AT(7, 19,20,21,22) AT(8, 20,21,22,23) }
            { float4 w = *((const float4*)&w2s[wbase + ((icw*16 + 8) ^ wswz)]);
              AT(0, 12,13,14,15) AT(1, 13,14,15,16) AT(2, 14,15,16,17)
              AT(3, 18,19,20,21) AT(4, 19,20,21,22) AT(5, 20,21,22,23)
              AT(6, 24,25,26,27) AT(7, 25,26,27,28) AT(8, 26,27,28,29) }
            { float4 w = *((const float4*)&w2s[wbase + ((icw*16 + 12) ^ wswz)]);
              AT(0, 18,19,20,21) AT(1, 19,20,21,22) AT(2, 20,21,22,23)
              AT(3, 24,25,26,27) AT(4, 25,26,27,28) AT(5, 26,27,28,29)
              AT(6, 30,31,32,33) AT(7, 31,32,33,34) AT(8, 32,33,34,35) }
        }
        __syncthreads();
    }

    {
        float* rp = &red[t*9];
        rp[0]=a0; rp[1]=a1; rp[2]=a2; rp[3]=a3; rp[4]=a4;
        rp[5]=a5; rp[6]=a6; rp[7]=a7; rp[8]=a8;
    }
    __syncthreads();
    for (int idx = t; idx < 288; idx += 256) {
        const int o2 = idx / 9, pos = idx % 9;
        float v = 0.f;
        #pragma unroll
        for (int k = 0; k < 8; k++) v += red[k*288 + idx];
        f_ws[n*577 + (oc0 + o2)*9 + pos] = LRELU(v);
    }

    if (bid < 8) {
        for (int idx = t; idx < 2436; idx += 256) {
            const int g = bid*2436 + idx;
            const int u = g & 31, a = g >> 5;
            W1T[g] = W1[u*609 + a];
        }
    }
}

// ---------------- Kernel B: M = F @ T, v3 (round-17) -----------------------
__global__ __launch_bounds__(1024) void mgemm_kernel(
    const float* __restrict__ F, const float* __restrict__ T,
    float* __restrict__ M)
{
    const int t = threadIdx.x;
    const int rb = blockIdx.x >> 2;          // 64 row tiles of 8
    const int cb = blockIdx.x & 3;           // 4 col tiles of 128
    const int ws = __builtin_amdgcn_readfirstlane(t >> 6);  // wave 0..15
    const int lane = t & 63;
    const int c0 = cb*128 + lane*2;
    const int k0 = ws*36;
    const int k1 = (ws == 15) ? 577 : (k0 + 36);
    const int r0 = rb*8;
    __shared__ float red[8*1032];

    const float* fbase = F + r0*577;
    float x0=0.f,y0=0.f, x1=0.f,y1=0.f, x2=0.f,y2=0.f, x3=0.f,y3=0.f,
          x4=0.f,y4=0.f, x5=0.f,y5=0.f, x6=0.f,y6=0.f, x7=0.f,y7=0.f;
    #pragma unroll 4
    for (int k = k0; k < k1; ++k) {
        const float2 tv = *(const float2*)&T[k*512 + c0];
        const float* fr = fbase + k;
        const float f0v = fr[0],    f1v = fr[577],  f2v = fr[1154], f3v = fr[1731];
        const float f4v = fr[2308], f5v = fr[2885], f6v = fr[3462], f7v = fr[4039];
        x0 += f0v*tv.x; y0 += f0v*tv.y;
        x1 += f1v*tv.x; y1 += f1v*tv.y;
        x2 += f2v*tv.x; y2 += f2v*tv.y;
        x3 += f3v*tv.x; y3 += f3v*tv.y;
        x4 += f4v*tv.x; y4 += f4v*tv.y;
        x5 += f5v*tv.x; y5 += f5v*tv.y;
        x6 += f6v*tv.x; y6 += f6v*tv.y;
        x7 += f7v*tv.x; y7 += f7v*tv.y;
    }

    const int cl2 = lane*2;
    if (ws < 8) {
        float* rp = &red[ws*1032];
        *(float2*)&rp[0*128 + cl2] = make_float2(x0, y0);
        *(float2*)&rp[1*128 + cl2] = make_float2(x1, y1);
        *(float2*)&rp[2*128 + cl2] = make_float2(x2, y2);
        *(float2*)&rp[3*128 + cl2] = make_float2(x3, y3);
        *(float2*)&rp[4*128 + cl2] = make_float2(x4, y4);
        *(float2*)&rp[5*128 + cl2] = make_float2(x5, y5);
        *(float2*)&rp[6*128 + cl2] = make_float2(x6, y6);
        *(float2*)&rp[7*128 + cl2] = make_float2(x7, y7);
    }
    __syncthreads();
    if (ws >= 8) {
        float* rp = &red[(ws-8)*1032];
        float2 v;
        v = *(float2*)&rp[0*128 + cl2]; v.x += x0; v.y += y0; *(float2*)&rp[0*128 + cl2] = v;
        v = *(float2*)&rp[1*128 + cl2]; v.x += x1; v.y += y1; *(float2*)&rp[1*128 + cl2] = v;
        v = *(float2*)&rp[2*128 + cl2]; v.x += x2; v.y += y2; *(float2*)&rp[2*128 + cl2] = v;
        v = *(float2*)&rp[3*128 + cl2]; v.x += x3; v.y += y3; *(float2*)&rp[3*128 + cl2] = v;
        v = *(float2*)&rp[4*128 + cl2]; v.x += x4; v.y += y4; *(float2*)&rp[4*128 + cl2] = v;
        v = *(float2*)&rp[5*128 + cl2]; v.x += x5; v.y += y5; *(float2*)&rp[5*128 + cl2] = v;
        v = *(float2*)&rp[6*128 + cl2]; v.x += x6; v.y += y6; *(float2*)&rp[6*128 + cl2] = v;
        v = *(float2*)&rp[7*128 + cl2]; v.x += x7; v.y += y7; *(float2*)&rp[7*128 + cl2] = v;
    }
    __syncthreads();
    {
        const int row = t >> 7, col = t & 127;
        const int o = row*128 + col;
        float v = 0.f;
        #pragma unroll
        for (int p = 0; p < 8; p++) v += red[p*1032 + o];
        M[(r0 + row)*512 + cb*128 + col] = v;
    }
}

// ---------------- Kernel C: pairwise (round-14 body, grid 512) -------------
#define LDM(R0, R1, R2, R3, JOFF) { \
    const float4* p_ = (const float4*)&M[(j0+jl+(JOFF))*512 + b*16]; \
    R0 = p_[0]; R1 = p_[1]; R2 = p_[2]; R3 = p_[3]; }

#define S16(P0, P1, P2, P3) \
  (fabsf(v0.x-P0.x)+fabsf(v0.y-P0.y)+fabsf(v0.z-P0.z)+fabsf(v0.w-P0.w) \
  +fabsf(v1.x-P1.x)+fabsf(v1.y-P1.y)+fabsf(v1.z-P1.z)+fabsf(v1.w-P1.w) \
  +fabsf(v2.x-P2.x)+fabsf(v2.y-P2.y)+fabsf(v2.z-P2.z)+fabsf(v2.w-P2.w) \
  +fabsf(v3.x-P3.x)+fabsf(v3.y-P3.y)+fabsf(v3.z-P3.z)+fabsf(v3.w-P3.w))

__global__ __launch_bounds__(256) void pairwise_kernel(
    const float* __restrict__ M, float* __restrict__ o_part) // (32,512,32)
{
    const int jt  = blockIdx.x >> 5;
    const int isp = blockIdx.x & 31;
    const int t = threadIdx.x;
    const int b = t & 31, jl = t >> 5;
    const int j0 = jt * 32;
    __shared__ float mi[16*572];

    float4 mA0,mA1,mA2,mA3, mB0,mB1,mB2,mB3, mC0,mC1,mC2,mC3, mD0,mD1,mD2,mD3;
    LDM(mA0,mA1,mA2,mA3, 0)
    LDM(mB0,mB1,mB2,mB3, 8)
    LDM(mC0,mC1,mC2,mC3, 16)
    LDM(mD0,mD1,mD2,mD3, 24)

    const int i0 = isp * 16;
    #pragma unroll
    for (int k = 0; k < 8; k++) {
        const int q = k*256 + t;
        const int r = q >> 7;
        const int x = (q & 127) * 4;
        float4 v = *(const float4*)&M[(i0+r)*512 + x];
        *(float4*)&mi[r*572 + x + ((x>>5)<<2)] = v;
    }
    __syncthreads();

    float acc0 = 0.f, acc1 = 0.f, acc2 = 0.f, acc3 = 0.f;
    const int lbase = b*16 + ((b>>1)<<2);

    #pragma unroll 4
    for (int r = 0; r < 16; r++) {
        const float4* q_ = (const float4*)&mi[r*572 + lbase];
        const float4 v0 = q_[0], v1 = q_[1], v2 = q_[2], v3 = q_[3];
        acc0 += __expf(-(S16(mA0,mA1,mA2,mA3)));
        acc1 += __expf(-(S16(mB0,mB1,mB2,mB3)));
        acc2 += __expf(-(S16(mC0,mC1,mC2,mC3)));
        acc3 += __expf(-(S16(mD0,mD1,mD2,mD3)));
    }
    const int ob = isp*16384 + b;
    o_part[ob + (j0+jl   )*32] = acc0;
    o_part[ob + (j0+jl+8 )*32] = acc1;
    o_part[ob + (j0+jl+16)*32] = acc2;
    o_part[ob + (j0+jl+24)*32] = acc3;
}

// ---------------- Kernel D: MLP head (round-14 body) -----------------------
__global__ __launch_bounds__(256) void mlp_kernel(
    const float* __restrict__ f, const float* __restrict__ o_part,
    const float* __restrict__ W1T, const float* __restrict__ b1v,
    const float* __restrict__ W2, const float* __restrict__ b2v,
    float* __restrict__ out)
{
    const int j = blockIdx.x;
    const int t = threadIdx.x;
    __shared__ float xs[609];
    __shared__ float red[256];

    for (int a = t; a < 577; a += 256) xs[a] = f[j*577 + a];
    {
        const int bb = t & 31, g = t >> 5;
        float ov = 0.f;
        #pragma unroll
        for (int k = 0; k < 4; k++)
            ov += o_part[(g + 8*k)*16384 + j*32 + bb];
        red[t] = ov;
    }
    __syncthreads();
    if (t < 32) {
        float ov = 0.f;
        #pragma unroll
        for (int g = 0; g < 8; g++) ov += red[t + g*32];
        xs[577 + t] = ov;
    }
    __syncthreads();

    const int u = t & 31, seg = t >> 5;
    float p = 0.f;
    #pragma unroll 4
    for (int a = seg; a < 609; a += 8)
        p += xs[a] * W1T[a*32 + u];
    red[t] = p;
    __syncthreads();

    if (t < 32) {
        float hid = red[t];
        #pragma unroll
        for (int s = 1; s < 8; s++) hid += red[t + s*32];
        hid += b1v[t];
        hid = LRELU(hid);
        float pr = hid * W2[t];
        #pragma unroll
        for (int mk = 16; mk; mk >>= 1) pr += __shfl_xor(pr, mk);
        if (t == 0) out[j] = 1.f / (1.f + __expf(-(pr + b2v[0])));
    }
}

extern "C" void kernel_launch(void* const* d_in, const int* in_sizes, int n_in,
                              void* d_out, int out_size, void* d_ws, size_t ws_size,
                              hipStream_t stream) {
    const float* readout = (const float*)d_in[0];
    const float* energy  = (const float*)d_in[1];
    const float* w1      = (const float*)d_in[2];
    const float* w2      = (const float*)d_in[3];
    const float* Tm      = (const float*)d_in[4];
    const float* W1      = (const float*)d_in[5];
    const float* b1v     = (const float*)d_in[6];
    const float* W2      = (const float*)d_in[7];
    const float* b2v     = (const float*)d_in[8];
    float* out = (float*)d_out;

    char* ws = (char*)d_ws;
    float* f_ws   = (float*)(ws);                                       // 512*577
    float* M_ws   = (float*)(ws + 512*577*4);                           // 512*512
    float* o_ws   = (float*)(ws + 512*577*4 + 512*512*4);               // 32*512*32
    float* W1T_ws = (float*)(ws + 512*577*4 + 512*512*4 + 32*512*32*4); // 609*32

    convf_kernel   <<<1024, 256, 0, stream>>>(readout, energy, w1, w2, W1, f_ws, W1T_ws);
    mgemm_kernel   <<<256, 1024, 0, stream>>>(f_ws, Tm, M_ws);
    pairwise_kernel<<<512, 256, 0, stream>>>(M_ws, o_ws);
    mlp_kernel     <<<512, 256, 0, stream>>>(f_ws, o_ws, W1T_ws, b1v, W2, b2v, out);
}